// Round 8
// baseline (2458.716 us; speedup 1.0000x reference)
//
#include <hip/hip_runtime.h>
#include <math.h>

// ---------------------------------------------------------------------------
// AttentionFlow v8.
//  v7 counters: gemm latency-bound (Mfma 14%, VALU 16%, HBM 9%, occ 22%).
//  v8: occupancy attack. gemm_kernel -> 512 thr / 8 waves, wave = 64r x 32c
//  (acc 64->32 AGPRs), LDS bounce removed (direct 64B-segment u32 stores,
//  LDS 34KB->1KB), __launch_bounds__(512,4) caps VGPR at 128 -> 4 waves/SIMD.
//  Lr u32-packed for both passes. part = 16 fixed-order partials.
//  XCD swizzle (v7) kept: 4 nb-blocks of a row tile -> same XCD L2.
// ---------------------------------------------------------------------------

#define NNODES 100000
#define DDIM   256
#define NH     512
#define NGROUP 64
#define EPG    1024
#define E1N    65536
#define E0N    65536
#define KTOP   256
#define ETOT   65536

typedef __attribute__((ext_vector_type(8))) _Float16 h8v;
typedef __attribute__((ext_vector_type(4))) float f32x4;
typedef __attribute__((ext_vector_type(4))) int i4v;

__device__ __forceinline__ float lrelu(float x) { return x > 0.0f ? x : 0.01f * x; }

__device__ __forceinline__ unsigned fenc(float f) {
  unsigned u = __float_as_uint(f);
  return (u & 0x80000000u) ? ~u : (u | 0x80000000u);
}
__device__ __forceinline__ float fdec(unsigned k) {
  unsigned u = (k & 0x80000000u) ? (k & 0x7FFFFFFFu) : ~k;
  return __uint_as_float(u);
}

__device__ __forceinline__ void splitf(float v, unsigned short& h, unsigned short& l) {
  _Float16 hh = (_Float16)v;
  _Float16 ll = (_Float16)(v - (float)hh);
  h = __builtin_bit_cast(unsigned short, hh);
  l = __builtin_bit_cast(unsigned short, ll);
}

__device__ __forceinline__ unsigned packsplit(float v) {
  unsigned short h, l;
  splitf(v, h, l);
  return ((unsigned)h << 16) | (unsigned)l;
}

__device__ __forceinline__ f32x4 mfma16(h8v a, h8v b, f32x4 c) {
  return __builtin_amdgcn_mfma_f32_16x16x32_f16(a, b, c, 0, 0, 0);
}

// ---------------------------------------------------------------------------
// qterm[g][o] = b[o] + qs[g] @ W[512:768] + qr[g] @ W[768:1024]
// ---------------------------------------------------------------------------
__global__ __launch_bounds__(512)
void qterm_kernel(const float* __restrict__ qse, const float* __restrict__ qre,
                  const float* __restrict__ Wl, const float* __restrict__ bl,
                  const float* __restrict__ Wr, const float* __restrict__ br,
                  float* __restrict__ qtl, float* __restrict__ qtr)
{
  const int g = blockIdx.x;
  const int o = threadIdx.x;
  __shared__ float sq[DDIM];
  __shared__ float sr[DDIM];
  if (o < DDIM) sq[o] = qse[(size_t)g * DDIM + o];
  else          sr[o - DDIM] = qre[(size_t)g * DDIM + (o - DDIM)];
  __syncthreads();
  float al = bl[o], ar = br[o];
  for (int k = 0; k < DDIM; ++k) {
    float a = sq[k], b = sr[k];
    al += a * Wl[(size_t)(512 + k) * NH + o] + b * Wl[(size_t)(768 + k) * NH + o];
    ar += a * Wr[(size_t)(512 + k) * NH + o] + b * Wr[(size_t)(768 + k) * NH + o];
  }
  qtl[(size_t)g * NH + o] = al;
  qtr[(size_t)g * NH + o] = ar;
}

// ---------------------------------------------------------------------------
// weight prep: Wt{H,L}[o][k] = splitf16(W[k][o]) for Wl[0:512], Wr[0:512], Wc
// ---------------------------------------------------------------------------
__global__ __launch_bounds__(256)
void wprep_kernel(const float* __restrict__ Wl, const float* __restrict__ Wr,
                  const float* __restrict__ Wc,
                  unsigned short* __restrict__ WltH, unsigned short* __restrict__ WltL,
                  unsigned short* __restrict__ WrtH, unsigned short* __restrict__ WrtL,
                  unsigned short* __restrict__ WctH, unsigned short* __restrict__ WctL)
{
  __shared__ float shv[32][33];
  const int mtx = blockIdx.y;
  const int ti = blockIdx.x >> 4;     // k tile
  const int tj = blockIdx.x & 15;     // o tile
  const float* W = mtx == 0 ? Wl : (mtx == 1 ? Wr : Wc);
  unsigned short* OH = mtx == 0 ? WltH : (mtx == 1 ? WrtH : WctH);
  unsigned short* OL = mtx == 0 ? WltL : (mtx == 1 ? WrtL : WctL);
  const int t = threadIdx.x;
  const int r = t >> 3, c4 = (t & 7) * 4;
  *(float4*)&shv[r][c4] = *(const float4*)(W + (size_t)(ti * 32 + r) * 512 + tj * 32 + c4);
  __syncthreads();
  unsigned short h[4], l[4];
#pragma unroll
  for (int q = 0; q < 4; ++q) splitf(shv[c4 + q][r], h[q], l[q]);
  const size_t off = (size_t)(tj * 32 + r) * 512 + ti * 32 + c4;
  *(uint2*)(OH + off) = make_uint2((unsigned)h[0] | ((unsigned)h[1] << 16),
                                   (unsigned)h[2] | ((unsigned)h[3] << 16));
  *(uint2*)(OL + off) = make_uint2((unsigned)l[0] | ((unsigned)l[1] << 16),
                                   (unsigned)l[2] | ((unsigned)l[3] << 16));
}

// WlinT[o][k] = f16(Wlin[k][o]), 256x256, hi only
__global__ __launch_bounds__(256)
void wlinprep_kernel(const float* __restrict__ Wlin, unsigned short* __restrict__ WlinT)
{
  __shared__ float shv[32][33];
  const int ti = blockIdx.x >> 3;    // k tile
  const int tj = blockIdx.x & 7;     // o tile
  const int t = threadIdx.x;
  const int r = t >> 3, c4 = (t & 7) * 4;
  *(float4*)&shv[r][c4] = *(const float4*)(Wlin + (size_t)(ti * 32 + r) * 256 + tj * 32 + c4);
  __syncthreads();
  unsigned short o[4];
#pragma unroll
  for (int q = 0; q < 4; ++q)
    o[q] = __builtin_bit_cast(unsigned short, (_Float16)shv[c4 + q][r]);
  *(uint2*)(WlinT + (size_t)(tj * 32 + r) * 256 + ti * 32 + c4) =
      make_uint2((unsigned)o[0] | ((unsigned)o[1] << 16),
                 (unsigned)o[2] | ((unsigned)o[3] << 16));
}

// ---------------------------------------------------------------------------
// f16 MFMA GEMM, 128x128 tile, 512 thr / 8 waves (2 row x 4 col),
// wave = 64 rows x 32 cols = 4mt x 2nt 16x16x32 tiles (acc 32 AGPRs).
// SPLIT=1: hi/lo split, 3 MFMAs/product (pass1). SPLIT=0: plain f16 (pass0).
// Lr is u32-packed (hi16|lo16) for BOTH splits.
// MODE 0: A = gather([emb[jcol]|rel]); epi: leaky(+qt) -> Lr (u32 direct store)
// MODE 1: A = Lr (extract hi/lo);      epi: +bc -> Rout f32 (direct store)
// MODE 2: A = gather([emb[icol]|rel]); epi: leaky(+qt), dot Rin,
//         16-lane reduce -> part[nb*4+wn][edge]   (deterministic)
// XCD swizzle: 4 nb-blocks of one row tile -> same XCD, adjacent slots.
// ---------------------------------------------------------------------------
template<int MODE, int SPLIT>
__global__ __launch_bounds__(512, 4)
void gemm_kernel(const int* __restrict__ edges, int ebase,
                 const float* __restrict__ emb, const float* __restrict__ rel,
                 const unsigned* __restrict__ Apack,
                 const unsigned short* __restrict__ BtH,
                 const unsigned short* __restrict__ BtL,
                 const float* __restrict__ qt, const float* __restrict__ bcv,
                 unsigned* __restrict__ OutU,
                 const float* __restrict__ Rin,
                 float* __restrict__ part)
{
  __shared__ int sidx[128];
  __shared__ int sgrp[128];

  const int tid  = threadIdx.x;
  const int lane = tid & 63;
  const int wid  = tid >> 6;
  const int wm = wid >> 2, wn = wid & 3;
  const int T   = gridDim.x >> 2;          // row tiles (multiple of 8)
  const int xcd = blockIdx.x & 7;
  const int slt = blockIdx.x >> 3;
  const int mb  = xcd * (T >> 3) + (slt >> 2);
  const int nb  = slt & 3;
  const int rb = mb * 128;
  const int arow = lane & 15;
  const int kgrp = (lane >> 4) * 8;
  const int col0 = nb * 128 + wn * 32;
  const int row0 = wm * 64;

  if (MODE != 1) {
    if (tid < 128) {
      const int* er = edges + (size_t)(ebase + rb + tid) * 8;
      sidx[tid] = er[MODE == 0 ? 7 : 6];
      sgrp[tid] = er[0];
    }
    __syncthreads();
  }

  // per-mt source base pointers (compile-time indexed)
  const float* pE[4];      // emb row base (k0 < 256)
  const float* pR[4];      // rel row base - 256 (k0 >= 256)
  const unsigned* pP[4];   // packed Lr row base (MODE 1)
#pragma unroll
  for (int mt = 0; mt < 4; ++mt) {
    const int rl = row0 + mt * 16 + arow;
    if (MODE == 1) {
      pP[mt] = Apack + (size_t)(rb + rl) * 512;
    } else {
      pE[mt] = emb + (size_t)sidx[rl] * DDIM;
      pR[mt] = rel + (size_t)(ebase + rb + rl) * DDIM - 256;
    }
  }

  f32x4 acc[4][2];
#pragma unroll
  for (int a = 0; a < 4; ++a)
#pragma unroll
    for (int b = 0; b < 2; ++b) acc[a][b] = (f32x4)0.0f;

  for (int ks = 0; ks < 16; ++ks) {
    const int k0 = ks * 32 + kgrp;
    h8v bh[2], bl[2];
#pragma unroll
    for (int nt = 0; nt < 2; ++nt) {
      const size_t boff = (size_t)(col0 + nt * 16 + arow) * 512 + k0;
      bh[nt] = *(const h8v*)(BtH + boff);
      if (SPLIT) bl[nt] = *(const h8v*)(BtL + boff);
    }
    // issue all A loads together (8 loads in flight)
    uint4 ar0[4], ar1[4];
#pragma unroll
    for (int mt = 0; mt < 4; ++mt) {
      const uint4* src;
      if (MODE == 1) src = (const uint4*)(pP[mt] + k0);
      else src = (const uint4*)((k0 < 256 ? pE[mt] : pR[mt]) + k0);
      ar0[mt] = src[0];
      ar1[mt] = src[1];
    }
#pragma unroll
    for (int mt = 0; mt < 4; ++mt) {
      unsigned u[8] = {ar0[mt].x, ar0[mt].y, ar0[mt].z, ar0[mt].w,
                       ar1[mt].x, ar1[mt].y, ar1[mt].z, ar1[mt].w};
      h8v h, l;
      if (MODE == 1) {
        i4v hv, lv;
#pragma unroll
        for (int d = 0; d < 4; ++d) {
          hv[d] = (int)((u[2*d] >> 16) | (u[2*d+1] & 0xffff0000u));
          if (SPLIT) lv[d] = (int)((u[2*d] & 0xffffu) | (u[2*d+1] << 16));
        }
        h = __builtin_bit_cast(h8v, hv);
        if (SPLIT) l = __builtin_bit_cast(h8v, lv);
      } else {
#pragma unroll
        for (int d = 0; d < 8; ++d) {
          float v = __uint_as_float(u[d]);
          _Float16 hh = (_Float16)v;
          h[d] = hh;
          if (SPLIT) l[d] = (_Float16)(v - (float)hh);
        }
      }
#pragma unroll
      for (int nt = 0; nt < 2; ++nt) {
        acc[mt][nt] = mfma16(h, bh[nt], acc[mt][nt]);
        if (SPLIT) {
          acc[mt][nt] = mfma16(h, bl[nt], acc[mt][nt]);
          acc[mt][nt] = mfma16(l, bh[nt], acc[mt][nt]);
        }
      }
    }
  }

  if (MODE == 2) {
#pragma unroll
    for (int mt = 0; mt < 4; ++mt) {
#pragma unroll
      for (int reg = 0; reg < 4; ++reg) {
        const int rl = row0 + mt * 16 + (lane >> 4) * 4 + reg;
        const int g = sgrp[rl];
        float s = 0.0f;
#pragma unroll
        for (int nt = 0; nt < 2; ++nt) {
          const int c = col0 + nt * 16 + arow;
          float v = lrelu(acc[mt][nt][reg] + qt[(size_t)g * NH + c]);
          s += v * Rin[(size_t)(rb + rl) * 512 + c];
        }
        s += __shfl_xor(s, 1); s += __shfl_xor(s, 2);
        s += __shfl_xor(s, 4); s += __shfl_xor(s, 8);
        if ((lane & 15) == 0)
          part[(size_t)(nb * 4 + wn) * ETOT + ebase + rb + rl] = s;
      }
    }
    return;
  }

  // MODE 0 / 1: direct u32 stores (16 consecutive lanes -> 64B segments)
#pragma unroll
  for (int mt = 0; mt < 4; ++mt)
#pragma unroll
    for (int nt = 0; nt < 2; ++nt) {
      const int c = col0 + nt * 16 + arow;
#pragma unroll
      for (int reg = 0; reg < 4; ++reg) {
        const int rl = row0 + mt * 16 + (lane >> 4) * 4 + reg;
        float v = acc[mt][nt][reg];
        unsigned pk;
        if (MODE == 0) {
          v = lrelu(v + qt[(size_t)sgrp[rl] * NH + c]);
          pk = packsplit(v);
        } else {
          pk = __float_as_uint(v + bcv[c]);
        }
        OutU[(size_t)(rb + rl) * 512 + c] = pk;
      }
    }
}

// logits[e] = sum_p part[p][e] (fixed order), then segment-max via atomicMax
__global__ void reduce_max_kernel(const float* __restrict__ part,
                                  const int* __restrict__ edges,
                                  float* __restrict__ logits,
                                  unsigned* __restrict__ mkey, int E)
{
  int e = blockIdx.x * blockDim.x + threadIdx.x;
  if (e < E) {
    float s = 0.0f;
#pragma unroll
    for (int p = 0; p < 16; ++p) s += part[(size_t)p * ETOT + e];
    logits[e] = s;
    atomicMax(mkey + edges[(size_t)e * 8 + 6], fenc(s));
  }
}

__global__ void smax_exp_kernel(const int* __restrict__ edges, const float* __restrict__ logits,
                                const unsigned* __restrict__ mkey, float* __restrict__ ssum,
                                float* __restrict__ sm, int* __restrict__ cnt, int E)
{
  int e = blockIdx.x * blockDim.x + threadIdx.x;
  if (e < E) {
    int s = edges[(size_t)e * 8 + 6];
    float ev = expf(logits[e] - fdec(mkey[s]));
    sm[e] = ev;
    atomicAdd(ssum + s, ev);
    if (cnt) atomicAdd(cnt + edges[(size_t)e * 8 + 7], 1);
  }
}

__global__ void smax_norm_kernel(const int* __restrict__ edges, const float* __restrict__ ssum,
                                 float* __restrict__ sm, const float* __restrict__ nscore,
                                 float* __restrict__ ta, int E)
{
  int e = blockIdx.x * blockDim.x + threadIdx.x;
  if (e < E) {
    int s = edges[(size_t)e * 8 + 6];
    float v = sm[e] / ssum[s];
    sm[e] = v;
    if (ta) ta[e] = v * nscore[s];
  }
}

// ---------------------------------------------------------------------------
// per-group top-256 of 1024 (desc value, ties -> low idx), bitonic sort
// ---------------------------------------------------------------------------
__global__ __launch_bounds__(256)
void topk_kernel(const float* __restrict__ ta, const float* __restrict__ sm1,
                 const int* __restrict__ edges1,
                 float* __restrict__ out0, float* __restrict__ out2,
                 float* __restrict__ out3, float* __restrict__ smp,
                 int* __restrict__ prn_i, int* __restrict__ prn_j,
                 int* __restrict__ cnt1)
{
  __shared__ float v[EPG];
  __shared__ int   ix[EPG];
  const int g = blockIdx.x, tid = threadIdx.x;
  for (int t = tid; t < EPG; t += 256) { v[t] = ta[(size_t)g * EPG + t]; ix[t] = t; }
  __syncthreads();
  for (int k = 2; k <= EPG; k <<= 1) {
    for (int j = k >> 1; j > 0; j >>= 1) {
      for (int t = tid; t < EPG; t += 256) {
        int l = t ^ j;
        if (l > t) {
          float va = v[t], vb = v[l];
          int ia = ix[t], ib = ix[l];
          bool aFirst = (va > vb) || (va == vb && ia < ib);
          bool up = ((t & k) == 0);
          bool sw = up ? !aFirst : aFirst;
          if (sw) { v[t] = vb; ix[t] = ib; v[l] = va; ix[l] = ia; }
        }
      }
      __syncthreads();
    }
  }
  const int r = tid;
  const int oi = ix[r];
  const float val = v[r];
  const int orig = g * EPG + oi;
  out3[(size_t)g * KTOP + r] = (float)orig;
  const int* er = edges1 + (size_t)orig * 8;
#pragma unroll
  for (int c = 0; c < 8; ++c)
    out2[((size_t)(g * KTOP + r)) * 8 + c] = (float)er[c];
  const int ii = er[6], jj = er[7];
  const float smv = sm1[orig];
  smp[(size_t)g * KTOP + r] = smv;
  prn_i[(size_t)g * KTOP + r] = ii;
  prn_j[(size_t)g * KTOP + r] = jj;
  atomicAdd(out0 + jj, smv * val);
  atomicAdd(cnt1 + jj, 1);
}

// 4 edges per block; thread o = dim o
__global__ void scatter_kernel(const int* __restrict__ idx_i, int si,
                               const int* __restrict__ idx_j, int sj,
                               const float* __restrict__ w,
                               const float* __restrict__ semb,
                               float* __restrict__ agg)
{
  const int e0 = blockIdx.x * 4;
  const int o = threadIdx.x;
#pragma unroll
  for (int q = 0; q < 4; ++q) {
    const int e = e0 + q;
    const int i = idx_i[(size_t)e * si];
    const int j = idx_j[(size_t)e * sj];
    atomicAdd(agg + (size_t)j * DDIM + o, w[e] * semb[(size_t)i * DDIM + o]);
  }
}

__global__ void combine_kernel(const float* __restrict__ mememb, const int* __restrict__ cnt,
                               float* __restrict__ agg)
{
  size_t id = (size_t)blockIdx.x * 256 + threadIdx.x;
  if (cnt[id >> 8] == 0) agg[id] = mememb[id];
}

// ---------------------------------------------------------------------------
// final (MFMA f16): out[r] = leaky( (cnt0[r]>0 ? agg0[r] : emb1[r]) @ Wlin + blin )
// ---------------------------------------------------------------------------
__global__ __launch_bounds__(512)
void final_mfma_kernel(const float* __restrict__ emb1, const float* __restrict__ agg0,
                       const int* __restrict__ cnt0,
                       const unsigned short* __restrict__ WlinT,
                       const float* __restrict__ blin, float* __restrict__ out)
{
  __shared__ int scnt[128];
  const int tid  = threadIdx.x;
  const int lane = tid & 63;
  const int wid  = tid >> 6;
  const int wm = wid >> 2, wn = wid & 3;
  const int rb = blockIdx.x * 128;
  const int arow = lane & 15;
  const int kgrp = (lane >> 4) * 8;
  const int row0 = wm * 64;
  const int col0 = wn * 64;

  if (tid < 128) {
    int r = rb + tid;
    scnt[tid] = (r < NNODES) ? cnt0[(r < NNODES) ? r : 0] : 0;
  }
  __syncthreads();

  f32x4 acc[4][4];
#pragma unroll
  for (int a = 0; a < 4; ++a)
#pragma unroll
    for (int b = 0; b < 4; ++b) acc[a][b] = (f32x4)0.0f;

  for (int ks = 0; ks < 8; ++ks) {
    const int k0 = ks * 32 + kgrp;
    h8v ah[4], bh[4];
#pragma unroll
    for (int nt = 0; nt < 4; ++nt)
      bh[nt] = *(const h8v*)(WlinT + (size_t)(col0 + nt * 16 + arow) * 256 + k0);
#pragma unroll
    for (int mt = 0; mt < 4; ++mt) {
      const int rl = row0 + mt * 16 + arow;
      int r = rb + rl;
      int rc = (r < NNODES) ? r : (NNODES - 1);
      const float* base = (scnt[rl] > 0) ? agg0 : emb1;
      const float* src = base + (size_t)rc * DDIM + k0;
      float4 f0 = *(const float4*)src;
      float4 f1 = *(const float4*)(src + 4);
      float v[8] = {f0.x, f0.y, f0.z, f0.w, f1.x, f1.y, f1.z, f1.w};
      h8v h;
#pragma unroll
      for (int d = 0; d < 8; ++d) h[d] = (_Float16)v[d];
      ah[mt] = h;
    }
#pragma unroll
    for (int mt = 0; mt < 4; ++mt)
#pragma unroll
      for (int nt = 0; nt < 4; ++nt)
        acc[mt][nt] = mfma16(ah[mt], bh[nt], acc[mt][nt]);
  }

  float bl4[4];
#pragma unroll
  for (int nt = 0; nt < 4; ++nt) bl4[nt] = blin[col0 + nt * 16 + arow];

#pragma unroll
  for (int mt = 0; mt < 4; ++mt)
#pragma unroll
    for (int reg = 0; reg < 4; ++reg) {
      const int r = rb + row0 + mt * 16 + (lane >> 4) * 4 + reg;
      if (r < NNODES) {
#pragma unroll
        for (int nt = 0; nt < 4; ++nt) {
          const int c = col0 + nt * 16 + arow;
          out[(size_t)r * DDIM + c] = lrelu(acc[mt][nt][reg] + bl4[nt]);
        }
      }
    }
}

// ---------------------------------------------------------------------------
extern "C" void kernel_launch(void* const* d_in, const int* in_sizes, int n_in,
                              void* d_out, int out_size, void* d_ws, size_t ws_size,
                              hipStream_t stream)
{
  (void)in_sizes; (void)n_in; (void)out_size;

  const float* node_score = (const float*)d_in[1];
  const int*   edges0 = (const int*)d_in[2];
  const int*   edges1 = (const int*)d_in[3];
  const float* rel0   = (const float*)d_in[4];
  const float* rel1   = (const float*)d_in[5];
  const float* mememb = (const float*)d_in[6];
  const float* qse    = (const float*)d_in[7];
  const float* qre    = (const float*)d_in[8];
  const float* Wl     = (const float*)d_in[9];
  const float* bl     = (const float*)d_in[10];
  const float* Wr     = (const float*)d_in[11];
  const float* br     = (const float*)d_in[12];
  const float* Wc     = (const float*)d_in[13];
  const float* bc     = (const float*)d_in[14];
  const float* Wlin   = (const float*)d_in[15];
  const float* blin   = (const float*)d_in[16];

  float* out0 = (float*)d_out;
  float* out1 = out0 + NNODES;
  float* out2 = out1 + (size_t)NNODES * DDIM;
  float* out3 = out2 + (size_t)NGROUP * KTOP * 8;

  char* wptr = (char*)d_ws;
  auto alloc = [&](size_t bytes) -> char* {
    char* p = wptr;
    wptr += (bytes + 255) & ~(size_t)255;
    return p;
  };
  float*    qtl     = (float*)alloc((size_t)NGROUP * NH * 4);
  float*    qtr     = (float*)alloc((size_t)NGROUP * NH * 4);
  float*    logits1 = (float*)alloc((size_t)E1N * 4);
  float*    sm1     = (float*)alloc((size_t)E1N * 4);
  float*    ta      = (float*)alloc((size_t)E1N * 4);
  float*    logits0 = (float*)alloc((size_t)E0N * 4);
  float*    sm0     = (float*)alloc((size_t)E0N * 4);
  unsigned* mkey    = (unsigned*)alloc((size_t)NNODES * 4);
  float*    ssum    = (float*)alloc((size_t)NNODES * 4);
  int*      cnt1    = (int*)alloc((size_t)NNODES * 4);
  int*      cnt0    = (int*)alloc((size_t)NNODES * 4);
  float*    smp     = (float*)alloc((size_t)NGROUP * KTOP * 4);
  int*      prn_i   = (int*)alloc((size_t)NGROUP * KTOP * 4);
  int*      prn_j   = (int*)alloc((size_t)NGROUP * KTOP * 4);
  float*    part    = (float*)alloc((size_t)16 * ETOT * 4);       // 4 MB
  float*    agg1    = (float*)alloc((size_t)NNODES * DDIM * 4);   // emb1

  unsigned short* WltH = (unsigned short*)alloc((size_t)512 * 512 * 2);
  unsigned short* WltL = (unsigned short*)alloc((size_t)512 * 512 * 2);
  unsigned short* WrtH = (unsigned short*)alloc((size_t)512 * 512 * 2);
  unsigned short* WrtL = (unsigned short*)alloc((size_t)512 * 512 * 2);
  unsigned short* WctH = (unsigned short*)alloc((size_t)512 * 512 * 2);
  unsigned short* WctL = (unsigned short*)alloc((size_t)512 * 512 * 2);
  unsigned short* WlnT = (unsigned short*)alloc((size_t)256 * 256 * 2);

  // adaptive chunking of the GEMM pipeline to fit workspace (try 1 first)
  size_t used = (size_t)(wptr - (char*)d_ws);
  int nchunks = 1;
  while (nchunks < 32 && used + 2 * ((size_t)(ETOT / nchunks) * 512 * 4 + 256) > ws_size)
    nchunks <<= 1;
  const int CE = ETOT / nchunks;
  unsigned* Lr   = (unsigned*)alloc((size_t)CE * 512 * 4);
  float*    Rout = (float*)alloc((size_t)CE * 512 * 4);

  // ---- pass 1 prep ----
  (void)hipMemsetAsync(agg1, 0, (size_t)NNODES * DDIM * 4, stream);
  (void)hipMemsetAsync(cnt1, 0, (size_t)NNODES * 4, stream);
  (void)hipMemsetAsync(mkey, 0, (size_t)NNODES * 4, stream);
  (void)hipMemsetAsync(ssum, 0, (size_t)NNODES * 4, stream);
  (void)hipMemsetAsync(out0, 0, (size_t)NNODES * 4, stream);

  qterm_kernel<<<NGROUP, 512, 0, stream>>>(qse, qre, Wl, bl, Wr, br, qtl, qtr);
  {
    dim3 g(256, 3);
    wprep_kernel<<<g, 256, 0, stream>>>(Wl, Wr, Wc, WltH, WltL, WrtH, WrtL, WctH, WctL);
  }
  wlinprep_kernel<<<64, 256, 0, stream>>>(Wlin, WlnT);

  // ---- pass 1: SPLIT=1 GEMM trio ----
  for (int ch = 0; ch < nchunks; ++ch) {
    const int eb = ch * CE;
    dim3 g((CE / 128) * 4);
    gemm_kernel<0,1><<<g, 512, 0, stream>>>(edges1, eb, mememb, rel1, nullptr,
                                            WrtH, WrtL, qtr, nullptr,
                                            Lr, nullptr, nullptr);
    gemm_kernel<1,1><<<g, 512, 0, stream>>>(edges1, eb, mememb, rel1, Lr,
                                            WctH, WctL, nullptr, bc,
                                            (unsigned*)Rout, nullptr, nullptr);
    gemm_kernel<2,1><<<g, 512, 0, stream>>>(edges1, eb, mememb, rel1, nullptr,
                                            WltH, WltL, qtl, nullptr,
                                            nullptr, Rout, part);
  }
  reduce_max_kernel<<<E1N / 256, 256, 0, stream>>>(part, edges1, logits1, mkey, E1N);
  smax_exp_kernel<<<E1N / 256, 256, 0, stream>>>(edges1, logits1, mkey, ssum, sm1,
                                                 nullptr, E1N);
  smax_norm_kernel<<<E1N / 256, 256, 0, stream>>>(edges1, ssum, sm1, node_score, ta, E1N);
  topk_kernel<<<NGROUP, 256, 0, stream>>>(ta, sm1, edges1, out0, out2, out3,
                                          smp, prn_i, prn_j, cnt1);
  scatter_kernel<<<NGROUP * KTOP / 4, 256, 0, stream>>>(prn_i, 1, prn_j, 1, smp,
                                                        mememb, agg1);
  combine_kernel<<<NNODES, 256, 0, stream>>>(mememb, cnt1, agg1);   // agg1 = emb1

  // ---- pass 0 prep ----
  (void)hipMemsetAsync(mkey, 0, (size_t)NNODES * 4, stream);
  (void)hipMemsetAsync(ssum, 0, (size_t)NNODES * 4, stream);
  (void)hipMemsetAsync(cnt0, 0, (size_t)NNODES * 4, stream);
  (void)hipMemsetAsync(out1, 0, (size_t)NNODES * DDIM * 4, stream);

  // ---- pass 0: SPLIT=0 GEMM trio ----
  for (int ch = 0; ch < nchunks; ++ch) {
    const int eb = ch * CE;
    dim3 g((CE / 128) * 4);
    gemm_kernel<0,0><<<g, 512, 0, stream>>>(edges0, eb, agg1, rel0, nullptr,
                                            WrtH, WrtL, qtr, nullptr,
                                            Lr, nullptr, nullptr);
    gemm_kernel<1,0><<<g, 512, 0, stream>>>(edges0, eb, agg1, rel0, Lr,
                                            WctH, WctL, nullptr, bc,
                                            (unsigned*)Rout, nullptr, nullptr);
    gemm_kernel<2,0><<<g, 512, 0, stream>>>(edges0, eb, agg1, rel0, nullptr,
                                            WltH, WltL, qtl, nullptr,
                                            nullptr, Rout, part);
  }
  reduce_max_kernel<<<E0N / 256, 256, 0, stream>>>(part, edges0, logits0, mkey, E0N);
  smax_exp_kernel<<<E0N / 256, 256, 0, stream>>>(edges0, logits0, mkey, ssum, sm0,
                                                 cnt0, E0N);
  smax_norm_kernel<<<E0N / 256, 256, 0, stream>>>(edges0, ssum, sm0, nullptr, nullptr, E0N);
  scatter_kernel<<<E0N / 4, 256, 0, stream>>>(edges0 + 6, 8, edges0 + 7, 8, sm0,
                                              agg1, out1);
  final_mfma_kernel<<<(NNODES + 127) / 128, 512, 0, stream>>>(agg1, out1, cnt0,
                                                              WlnT, blin, out1);
}

// Round 9
// 1101.855 us; speedup vs baseline: 2.2314x; 2.2314x over previous
//
#include <hip/hip_runtime.h>
#include <math.h>

// ---------------------------------------------------------------------------
// AttentionFlow v9: fused score pipeline.
//  v8 post-mortem: the GEMM-trio structure itself was the bound — each of 6
//  dispatches pays intermediate round-trips (Lr/Rout ~540 MB/pass) + gather.
//  v9 fuses GEMM1/2/3 per 64-edge block: A gathered to LDS (packed hi|lo,
//  XOR-swizzled), Lr written back into same LDS, Rout held in registers,
//  GEMM3 dot fused vs register Rout -> logits + atomicMax. No intermediates,
//  no part buffer, deterministic (fixed-order 8-wave reduce).
//  SPLIT=1 (pass1, top-k-exact: 3 MFMAs/product), SPLIT=0 (pass0: 1 MFMA).
// ---------------------------------------------------------------------------

#define NNODES 100000
#define DDIM   256
#define NH     512
#define NGROUP 64
#define EPG    1024
#define E1N    65536
#define E0N    65536
#define KTOP   256

typedef __attribute__((ext_vector_type(8))) _Float16 h8v;
typedef __attribute__((ext_vector_type(4))) float f32x4;
typedef __attribute__((ext_vector_type(4))) int i4v;

__device__ __forceinline__ float lrelu(float x) { return x > 0.0f ? x : 0.01f * x; }

__device__ __forceinline__ unsigned fenc(float f) {
  unsigned u = __float_as_uint(f);
  return (u & 0x80000000u) ? ~u : (u | 0x80000000u);
}
__device__ __forceinline__ float fdec(unsigned k) {
  unsigned u = (k & 0x80000000u) ? (k & 0x7FFFFFFFu) : ~k;
  return __uint_as_float(u);
}

__device__ __forceinline__ void splitf(float v, unsigned short& h, unsigned short& l) {
  _Float16 hh = (_Float16)v;
  _Float16 ll = (_Float16)(v - (float)hh);
  h = __builtin_bit_cast(unsigned short, hh);
  l = __builtin_bit_cast(unsigned short, ll);
}

__device__ __forceinline__ unsigned packsplit(float v) {
  unsigned short h, l;
  splitf(v, h, l);
  return ((unsigned)h << 16) | (unsigned)l;
}

__device__ __forceinline__ f32x4 mfma16(h8v a, h8v b, f32x4 c) {
  return __builtin_amdgcn_mfma_f32_16x16x32_f16(a, b, c, 0, 0, 0);
}

// ---------------------------------------------------------------------------
// qterm[g][o] = b[o] + qs[g] @ W[512:768] + qr[g] @ W[768:1024]
// ---------------------------------------------------------------------------
__global__ __launch_bounds__(512)
void qterm_kernel(const float* __restrict__ qse, const float* __restrict__ qre,
                  const float* __restrict__ Wl, const float* __restrict__ bl,
                  const float* __restrict__ Wr, const float* __restrict__ br,
                  float* __restrict__ qtl, float* __restrict__ qtr)
{
  const int g = blockIdx.x;
  const int o = threadIdx.x;
  __shared__ float sq[DDIM];
  __shared__ float sr[DDIM];
  if (o < DDIM) sq[o] = qse[(size_t)g * DDIM + o];
  else          sr[o - DDIM] = qre[(size_t)g * DDIM + (o - DDIM)];
  __syncthreads();
  float al = bl[o], ar = br[o];
  for (int k = 0; k < DDIM; ++k) {
    float a = sq[k], b = sr[k];
    al += a * Wl[(size_t)(512 + k) * NH + o] + b * Wl[(size_t)(768 + k) * NH + o];
    ar += a * Wr[(size_t)(512 + k) * NH + o] + b * Wr[(size_t)(768 + k) * NH + o];
  }
  qtl[(size_t)g * NH + o] = al;
  qtr[(size_t)g * NH + o] = ar;
}

// ---------------------------------------------------------------------------
// weight prep: Wt{H,L}[o][k] = splitf16(W[k][o]) for Wl[0:512], Wr[0:512], Wc
// ---------------------------------------------------------------------------
__global__ __launch_bounds__(256)
void wprep_kernel(const float* __restrict__ Wl, const float* __restrict__ Wr,
                  const float* __restrict__ Wc,
                  unsigned short* __restrict__ WltH, unsigned short* __restrict__ WltL,
                  unsigned short* __restrict__ WrtH, unsigned short* __restrict__ WrtL,
                  unsigned short* __restrict__ WctH, unsigned short* __restrict__ WctL)
{
  __shared__ float shv[32][33];
  const int mtx = blockIdx.y;
  const int ti = blockIdx.x >> 4;     // k tile
  const int tj = blockIdx.x & 15;     // o tile
  const float* W = mtx == 0 ? Wl : (mtx == 1 ? Wr : Wc);
  unsigned short* OH = mtx == 0 ? WltH : (mtx == 1 ? WrtH : WctH);
  unsigned short* OL = mtx == 0 ? WltL : (mtx == 1 ? WrtL : WctL);
  const int t = threadIdx.x;
  const int r = t >> 3, c4 = (t & 7) * 4;
  *(float4*)&shv[r][c4] = *(const float4*)(W + (size_t)(ti * 32 + r) * 512 + tj * 32 + c4);
  __syncthreads();
  unsigned short h[4], l[4];
#pragma unroll
  for (int q = 0; q < 4; ++q) splitf(shv[c4 + q][r], h[q], l[q]);
  const size_t off = (size_t)(tj * 32 + r) * 512 + ti * 32 + c4;
  *(uint2*)(OH + off) = make_uint2((unsigned)h[0] | ((unsigned)h[1] << 16),
                                   (unsigned)h[2] | ((unsigned)h[3] << 16));
  *(uint2*)(OL + off) = make_uint2((unsigned)l[0] | ((unsigned)l[1] << 16),
                                   (unsigned)l[2] | ((unsigned)l[3] << 16));
}

// WlinT[o][k] = f16(Wlin[k][o]), 256x256, hi only
__global__ __launch_bounds__(256)
void wlinprep_kernel(const float* __restrict__ Wlin, unsigned short* __restrict__ WlinT)
{
  __shared__ float shv[32][33];
  const int ti = blockIdx.x >> 3;    // k tile
  const int tj = blockIdx.x & 7;     // o tile
  const int t = threadIdx.x;
  const int r = t >> 3, c4 = (t & 7) * 4;
  *(float4*)&shv[r][c4] = *(const float4*)(Wlin + (size_t)(ti * 32 + r) * 256 + tj * 32 + c4);
  __syncthreads();
  unsigned short o[4];
#pragma unroll
  for (int q = 0; q < 4; ++q)
    o[q] = __builtin_bit_cast(unsigned short, (_Float16)shv[c4 + q][r]);
  *(uint2*)(WlinT + (size_t)(tj * 32 + r) * 256 + ti * 32 + c4) =
      make_uint2((unsigned)o[0] | ((unsigned)o[1] << 16),
                 (unsigned)o[2] | ((unsigned)o[3] << 16));
}

// ---------------------------------------------------------------------------
// Fused score kernel. Block = 64 edges x 512 cols, 512 thr / 8 waves.
// Wave w: rows 0..63 x cols w*64..w*64+63 (4mt x 4nt 16x16x32 tiles).
// LDS holds one 64x512 packed (hi16|lo16) operand tile, XOR-swizzled
// (k ^ ((row&7)<<2), 16B granules) to break stride-2KB bank conflicts.
// Phases: stage A_j -> GEMM1(Wr) -> Lr back into LDS -> GEMM2(Wc) -> Rout in
// regs -> stage A_i -> GEMM3(Wl) -> fused dot vs Rout -> fixed-order reduce
// -> logits + atomicMax(mkey). No global intermediates; deterministic.
// ---------------------------------------------------------------------------
template<int SPLIT>
__global__ __launch_bounds__(512, 2)
void fused_score_kernel(const int* __restrict__ edges,
                        const float* __restrict__ emb,
                        const float* __restrict__ rel,
                        const unsigned short* __restrict__ BrH,
                        const unsigned short* __restrict__ BrL,
                        const unsigned short* __restrict__ BcH,
                        const unsigned short* __restrict__ BcL,
                        const unsigned short* __restrict__ BlH,
                        const unsigned short* __restrict__ BlL,
                        const float* __restrict__ qtr,
                        const float* __restrict__ qtl,
                        const float* __restrict__ bcv,
                        float* __restrict__ logits,
                        unsigned* __restrict__ mkey)
{
  __shared__ unsigned lds[64 * 512];   // 128 KB packed operand tile
  __shared__ float red[8][64];
  __shared__ int sidx[64];
  __shared__ int sgrp[64];

  const int tid  = threadIdx.x;
  const int lane = tid & 63;
  const int w    = tid >> 6;
  const int arow = lane & 15;
  const int kgrp = (lane >> 4) * 8;
  const int col0 = w * 64;
  const int rb   = blockIdx.x * 64;

  // gather [emb[sidx[row]] | rel[row]] -> LDS packed+swizzled
  auto stage = [&]() {
    const int srow = tid >> 3;          // 0..63
    const int sseg = tid & 7;           // 64-float segment
    const float* src = (sseg < 4)
        ? emb + (size_t)sidx[srow] * DDIM + sseg * 64
        : rel + (size_t)(rb + srow) * DDIM + (sseg - 4) * 64;
    const int sw = (srow & 7) << 2;
#pragma unroll
    for (int q = 0; q < 16; ++q) {
      float4 f = ((const float4*)src)[q];
      uint4 o = make_uint4(packsplit(f.x), packsplit(f.y), packsplit(f.z), packsplit(f.w));
      *(uint4*)&lds[srow * 512 + ((sseg * 64 + q * 4) ^ sw)] = o;
    }
  };

  // acc += LDS-tile @ Bt (SPLIT: 3 MFMAs/product)
  auto gemm = [&](const unsigned short* BH, const unsigned short* BL, f32x4 (&acc)[4][4]) {
    for (int ks = 0; ks < 16; ++ks) {
      const int k0 = ks * 32 + kgrp;
      h8v bh[4], bl[4];
#pragma unroll
      for (int nt = 0; nt < 4; ++nt) {
        const size_t boff = (size_t)(col0 + nt * 16 + arow) * 512 + k0;
        bh[nt] = *(const h8v*)(BH + boff);
        if (SPLIT) bl[nt] = *(const h8v*)(BL + boff);
      }
#pragma unroll
      for (int mt = 0; mt < 4; ++mt) {
        const int row = mt * 16 + arow;
        const int sw = (row & 7) << 2;
        const unsigned* lp = &lds[row * 512];
        uint4 u0 = *(const uint4*)(lp + (k0 ^ sw));
        uint4 u1 = *(const uint4*)(lp + ((k0 + 4) ^ sw));
        unsigned u[8] = {u0.x, u0.y, u0.z, u0.w, u1.x, u1.y, u1.z, u1.w};
        i4v hv, lv;
#pragma unroll
        for (int d = 0; d < 4; ++d) {
          hv[d] = (int)((u[2*d] >> 16) | (u[2*d+1] & 0xffff0000u));
          if (SPLIT) lv[d] = (int)((u[2*d] & 0xffffu) | (u[2*d+1] << 16));
        }
        h8v h = __builtin_bit_cast(h8v, hv);
        h8v l;
        if (SPLIT) l = __builtin_bit_cast(h8v, lv);
#pragma unroll
        for (int nt = 0; nt < 4; ++nt) {
          acc[mt][nt] = mfma16(h, bh[nt], acc[mt][nt]);
          if (SPLIT) {
            acc[mt][nt] = mfma16(h, bl[nt], acc[mt][nt]);
            acc[mt][nt] = mfma16(l, bh[nt], acc[mt][nt]);
          }
        }
      }
    }
  };

  if (tid < 64) {
    const int* er = edges + (size_t)(rb + tid) * 8;
    sidx[tid] = er[7];                 // j column for A_j
    sgrp[tid] = er[0];
  }
  __syncthreads();
  stage();                             // A_j
  __syncthreads();

  // ---- GEMM1: Lr_pre = A_j @ WrT ----
  f32x4 a1[4][4];
#pragma unroll
  for (int a = 0; a < 4; ++a)
#pragma unroll
    for (int b = 0; b < 4; ++b) a1[a][b] = (f32x4)0.0f;
  gemm(BrH, BrL, a1);
  __syncthreads();                     // all waves done reading A_j
  // Lr = leaky(a1 + qtr) -> packed back into LDS
#pragma unroll
  for (int mt = 0; mt < 4; ++mt)
#pragma unroll
    for (int nt = 0; nt < 4; ++nt) {
      const int c = col0 + nt * 16 + arow;
#pragma unroll
      for (int reg = 0; reg < 4; ++reg) {
        const int row = mt * 16 + (lane >> 4) * 4 + reg;
        float v = lrelu(a1[mt][nt][reg] + qtr[(size_t)sgrp[row] * NH + c]);
        lds[row * 512 + (c ^ ((row & 7) << 2))] = packsplit(v);
      }
    }
  __syncthreads();

  // ---- GEMM2: Rout = Lr @ WcT + bc (stays in registers) ----
  f32x4 ro[4][4];
#pragma unroll
  for (int a = 0; a < 4; ++a)
#pragma unroll
    for (int b = 0; b < 4; ++b) ro[a][b] = (f32x4)0.0f;
  gemm(BcH, BcL, ro);
#pragma unroll
  for (int nt = 0; nt < 4; ++nt) {
    const float bcval = bcv[col0 + nt * 16 + arow];
#pragma unroll
    for (int mt = 0; mt < 4; ++mt)
#pragma unroll
      for (int reg = 0; reg < 4; ++reg) ro[mt][nt][reg] += bcval;
  }
  __syncthreads();                     // all waves done reading Lr
  if (tid < 64) sidx[tid] = edges[(size_t)(rb + tid) * 8 + 6];   // i column
  __syncthreads();
  stage();                             // A_i (overwrites Lr)
  __syncthreads();

  // ---- GEMM3 + fused dot vs Rout ----
  f32x4 a3[4][4];
#pragma unroll
  for (int a = 0; a < 4; ++a)
#pragma unroll
    for (int b = 0; b < 4; ++b) a3[a][b] = (f32x4)0.0f;
  gemm(BlH, BlL, a3);
#pragma unroll
  for (int mt = 0; mt < 4; ++mt) {
#pragma unroll
    for (int reg = 0; reg < 4; ++reg) {
      const int row = mt * 16 + (lane >> 4) * 4 + reg;
      const int g = sgrp[row];
      float s = 0.0f;
#pragma unroll
      for (int nt = 0; nt < 4; ++nt) {
        const int c = col0 + nt * 16 + arow;
        float v = lrelu(a3[mt][nt][reg] + qtl[(size_t)g * NH + c]);
        s += v * ro[mt][nt][reg];
      }
      s += __shfl_xor(s, 1); s += __shfl_xor(s, 2);
      s += __shfl_xor(s, 4); s += __shfl_xor(s, 8);
      if ((lane & 15) == 0) red[w][row] = s;
    }
  }
  __syncthreads();
  if (tid < 64) {
    float s = 0.0f;
#pragma unroll
    for (int p = 0; p < 8; ++p) s += red[p][tid];   // fixed order
    logits[rb + tid] = s;
    atomicMax(mkey + sidx[tid], fenc(s));           // sidx = er[6] = src node
  }
}

// ---------------------------------------------------------------------------
// segment softmax helpers
// ---------------------------------------------------------------------------
__global__ void smax_exp_kernel(const int* __restrict__ edges, const float* __restrict__ logits,
                                const unsigned* __restrict__ mkey, float* __restrict__ ssum,
                                float* __restrict__ sm, int* __restrict__ cnt, int E)
{
  int e = blockIdx.x * blockDim.x + threadIdx.x;
  if (e < E) {
    int s = edges[(size_t)e * 8 + 6];
    float ev = expf(logits[e] - fdec(mkey[s]));
    sm[e] = ev;
    atomicAdd(ssum + s, ev);
    if (cnt) atomicAdd(cnt + edges[(size_t)e * 8 + 7], 1);
  }
}

__global__ void smax_norm_kernel(const int* __restrict__ edges, const float* __restrict__ ssum,
                                 float* __restrict__ sm, const float* __restrict__ nscore,
                                 float* __restrict__ ta, int E)
{
  int e = blockIdx.x * blockDim.x + threadIdx.x;
  if (e < E) {
    int s = edges[(size_t)e * 8 + 6];
    float v = sm[e] / ssum[s];
    sm[e] = v;
    if (ta) ta[e] = v * nscore[s];
  }
}

// ---------------------------------------------------------------------------
// per-group top-256 of 1024 (desc value, ties -> low idx), bitonic sort
// ---------------------------------------------------------------------------
__global__ __launch_bounds__(256)
void topk_kernel(const float* __restrict__ ta, const float* __restrict__ sm1,
                 const int* __restrict__ edges1,
                 float* __restrict__ out0, float* __restrict__ out2,
                 float* __restrict__ out3, float* __restrict__ smp,
                 int* __restrict__ prn_i, int* __restrict__ prn_j,
                 int* __restrict__ cnt1)
{
  __shared__ float v[EPG];
  __shared__ int   ix[EPG];
  const int g = blockIdx.x, tid = threadIdx.x;
  for (int t = tid; t < EPG; t += 256) { v[t] = ta[(size_t)g * EPG + t]; ix[t] = t; }
  __syncthreads();
  for (int k = 2; k <= EPG; k <<= 1) {
    for (int j = k >> 1; j > 0; j >>= 1) {
      for (int t = tid; t < EPG; t += 256) {
        int l = t ^ j;
        if (l > t) {
          float va = v[t], vb = v[l];
          int ia = ix[t], ib = ix[l];
          bool aFirst = (va > vb) || (va == vb && ia < ib);
          bool up = ((t & k) == 0);
          bool sw = up ? !aFirst : aFirst;
          if (sw) { v[t] = vb; ix[t] = ib; v[l] = va; ix[l] = ia; }
        }
      }
      __syncthreads();
    }
  }
  const int r = tid;
  const int oi = ix[r];
  const float val = v[r];
  const int orig = g * EPG + oi;
  out3[(size_t)g * KTOP + r] = (float)orig;
  const int* er = edges1 + (size_t)orig * 8;
#pragma unroll
  for (int c = 0; c < 8; ++c)
    out2[((size_t)(g * KTOP + r)) * 8 + c] = (float)er[c];
  const int ii = er[6], jj = er[7];
  const float smv = sm1[orig];
  smp[(size_t)g * KTOP + r] = smv;
  prn_i[(size_t)g * KTOP + r] = ii;
  prn_j[(size_t)g * KTOP + r] = jj;
  atomicAdd(out0 + jj, smv * val);
  atomicAdd(cnt1 + jj, 1);
}

// 4 edges per block; thread o = dim o
__global__ void scatter_kernel(const int* __restrict__ idx_i, int si,
                               const int* __restrict__ idx_j, int sj,
                               const float* __restrict__ w,
                               const float* __restrict__ semb,
                               float* __restrict__ agg)
{
  const int e0 = blockIdx.x * 4;
  const int o = threadIdx.x;
#pragma unroll
  for (int q = 0; q < 4; ++q) {
    const int e = e0 + q;
    const int i = idx_i[(size_t)e * si];
    const int j = idx_j[(size_t)e * sj];
    atomicAdd(agg + (size_t)j * DDIM + o, w[e] * semb[(size_t)i * DDIM + o]);
  }
}

__global__ void combine_kernel(const float* __restrict__ mememb, const int* __restrict__ cnt,
                               float* __restrict__ agg)
{
  size_t id = (size_t)blockIdx.x * 256 + threadIdx.x;
  if (cnt[id >> 8] == 0) agg[id] = mememb[id];
}

// ---------------------------------------------------------------------------
// final (MFMA f16): out[r] = leaky( (cnt0[r]>0 ? agg0[r] : emb1[r]) @ Wlin + blin )
// ---------------------------------------------------------------------------
__global__ __launch_bounds__(512)
void final_mfma_kernel(const float* __restrict__ emb1, const float* __restrict__ agg0,
                       const int* __restrict__ cnt0,
                       const unsigned short* __restrict__ WlinT,
                       const float* __restrict__ blin, float* __restrict__ out)
{
  __shared__ int scnt[128];
  const int tid  = threadIdx.x;
  const int lane = tid & 63;
  const int wid  = tid >> 6;
  const int wm = wid >> 2, wn = wid & 3;
  const int rb = blockIdx.x * 128;
  const int arow = lane & 15;
  const int kgrp = (lane >> 4) * 8;
  const int row0 = wm * 64;
  const int col0 = wn * 64;

  if (tid < 128) {
    int r = rb + tid;
    scnt[tid] = (r < NNODES) ? cnt0[(r < NNODES) ? r : 0] : 0;
  }
  __syncthreads();

  f32x4 acc[4][4];
#pragma unroll
  for (int a = 0; a < 4; ++a)
#pragma unroll
    for (int b = 0; b < 4; ++b) acc[a][b] = (f32x4)0.0f;

  for (int ks = 0; ks < 8; ++ks) {
    const int k0 = ks * 32 + kgrp;
    h8v ah[4], bh[4];
#pragma unroll
    for (int nt = 0; nt < 4; ++nt)
      bh[nt] = *(const h8v*)(WlinT + (size_t)(col0 + nt * 16 + arow) * 256 + k0);
#pragma unroll
    for (int mt = 0; mt < 4; ++mt) {
      const int rl = row0 + mt * 16 + arow;
      int r = rb + rl;
      int rc = (r < NNODES) ? r : (NNODES - 1);
      const float* base = (scnt[rl] > 0) ? agg0 : emb1;
      const float* src = base + (size_t)rc * DDIM + k0;
      float4 f0 = *(const float4*)src;
      float4 f1 = *(const float4*)(src + 4);
      float v[8] = {f0.x, f0.y, f0.z, f0.w, f1.x, f1.y, f1.z, f1.w};
      h8v h;
#pragma unroll
      for (int d = 0; d < 8; ++d) h[d] = (_Float16)v[d];
      ah[mt] = h;
    }
#pragma unroll
    for (int mt = 0; mt < 4; ++mt)
#pragma unroll
      for (int nt = 0; nt < 4; ++nt)
        acc[mt][nt] = mfma16(ah[mt], bh[nt], acc[mt][nt]);
  }

  float bl4[4];
#pragma unroll
  for (int nt = 0; nt < 4; ++nt) bl4[nt] = blin[col0 + nt * 16 + arow];

#pragma unroll
  for (int mt = 0; mt < 4; ++mt)
#pragma unroll
    for (int reg = 0; reg < 4; ++reg) {
      const int r = rb + row0 + mt * 16 + (lane >> 4) * 4 + reg;
      if (r < NNODES) {
#pragma unroll
        for (int nt = 0; nt < 4; ++nt) {
          const int c = col0 + nt * 16 + arow;
          out[(size_t)r * DDIM + c] = lrelu(acc[mt][nt][reg] + bl4[nt]);
        }
      }
    }
}

// ---------------------------------------------------------------------------
extern "C" void kernel_launch(void* const* d_in, const int* in_sizes, int n_in,
                              void* d_out, int out_size, void* d_ws, size_t ws_size,
                              hipStream_t stream)
{
  (void)in_sizes; (void)n_in; (void)out_size; (void)ws_size;

  const float* node_score = (const float*)d_in[1];
  const int*   edges0 = (const int*)d_in[2];
  const int*   edges1 = (const int*)d_in[3];
  const float* rel0   = (const float*)d_in[4];
  const float* rel1   = (const float*)d_in[5];
  const float* mememb = (const float*)d_in[6];
  const float* qse    = (const float*)d_in[7];
  const float* qre    = (const float*)d_in[8];
  const float* Wl     = (const float*)d_in[9];
  const float* bl     = (const float*)d_in[10];
  const float* Wr     = (const float*)d_in[11];
  const float* br     = (const float*)d_in[12];
  const float* Wc     = (const float*)d_in[13];
  const float* bc     = (const float*)d_in[14];
  const float* Wlin   = (const float*)d_in[15];
  const float* blin   = (const float*)d_in[16];

  float* out0 = (float*)d_out;
  float* out1 = out0 + NNODES;
  float* out2 = out1 + (size_t)NNODES * DDIM;
  float* out3 = out2 + (size_t)NGROUP * KTOP * 8;

  char* wptr = (char*)d_ws;
  auto alloc = [&](size_t bytes) -> char* {
    char* p = wptr;
    wptr += (bytes + 255) & ~(size_t)255;
    return p;
  };
  float*    qtl     = (float*)alloc((size_t)NGROUP * NH * 4);
  float*    qtr     = (float*)alloc((size_t)NGROUP * NH * 4);
  float*    logits1 = (float*)alloc((size_t)E1N * 4);
  float*    sm1     = (float*)alloc((size_t)E1N * 4);
  float*    ta      = (float*)alloc((size_t)E1N * 4);
  float*    logits0 = (float*)alloc((size_t)E0N * 4);
  float*    sm0     = (float*)alloc((size_t)E0N * 4);
  unsigned* mkey    = (unsigned*)alloc((size_t)NNODES * 4);
  float*    ssum    = (float*)alloc((size_t)NNODES * 4);
  int*      cnt1    = (int*)alloc((size_t)NNODES * 4);
  int*      cnt0    = (int*)alloc((size_t)NNODES * 4);
  float*    smp     = (float*)alloc((size_t)NGROUP * KTOP * 4);
  int*      prn_i   = (int*)alloc((size_t)NGROUP * KTOP * 4);
  int*      prn_j   = (int*)alloc((size_t)NGROUP * KTOP * 4);
  float*    agg1    = (float*)alloc((size_t)NNODES * DDIM * 4);   // emb1

  unsigned short* WltH = (unsigned short*)alloc((size_t)512 * 512 * 2);
  unsigned short* WltL = (unsigned short*)alloc((size_t)512 * 512 * 2);
  unsigned short* WrtH = (unsigned short*)alloc((size_t)512 * 512 * 2);
  unsigned short* WrtL = (unsigned short*)alloc((size_t)512 * 512 * 2);
  unsigned short* WctH = (unsigned short*)alloc((size_t)512 * 512 * 2);
  unsigned short* WctL = (unsigned short*)alloc((size_t)512 * 512 * 2);
  unsigned short* WlnT = (unsigned short*)alloc((size_t)256 * 256 * 2);

  // ---- pass 1 prep ----
  (void)hipMemsetAsync(agg1, 0, (size_t)NNODES * DDIM * 4, stream);
  (void)hipMemsetAsync(cnt1, 0, (size_t)NNODES * 4, stream);
  (void)hipMemsetAsync(mkey, 0, (size_t)NNODES * 4, stream);
  (void)hipMemsetAsync(ssum, 0, (size_t)NNODES * 4, stream);
  (void)hipMemsetAsync(out0, 0, (size_t)NNODES * 4, stream);

  qterm_kernel<<<NGROUP, 512, 0, stream>>>(qse, qre, Wl, bl, Wr, br, qtl, qtr);
  {
    dim3 g(256, 3);
    wprep_kernel<<<g, 256, 0, stream>>>(Wl, Wr, Wc, WltH, WltL, WrtH, WrtL, WctH, WctL);
  }
  wlinprep_kernel<<<64, 256, 0, stream>>>(Wlin, WlnT);

  // ---- pass 1: fused score (split-f16, exact-ish logits for top-k) ----
  fused_score_kernel<1><<<E1N / 64, 512, 0, stream>>>(
      edges1, mememb, rel1, WrtH, WrtL, WctH, WctL, WltH, WltL,
      qtr, qtl, bc, logits1, mkey);

  smax_exp_kernel<<<E1N / 256, 256, 0, stream>>>(edges1, logits1, mkey, ssum, sm1,
                                                 nullptr, E1N);
  smax_norm_kernel<<<E1N / 256, 256, 0, stream>>>(edges1, ssum, sm1, node_score, ta, E1N);
  topk_kernel<<<NGROUP, 256, 0, stream>>>(ta, sm1, edges1, out0, out2, out3,
                                          smp, prn_i, prn_j, cnt1);
  scatter_kernel<<<NGROUP * KTOP / 4, 256, 0, stream>>>(prn_i, 1, prn_j, 1, smp,
                                                        mememb, agg1);
  combine_kernel<<<NNODES, 256, 0, stream>>>(mememb, cnt1, agg1);   // agg1 = emb1

  // ---- pass 0 prep ----
  (void)hipMemsetAsync(mkey, 0, (size_t)NNODES * 4, stream);
  (void)hipMemsetAsync(ssum, 0, (size_t)NNODES * 4, stream);
  (void)hipMemsetAsync(cnt0, 0, (size_t)NNODES * 4, stream);
  (void)hipMemsetAsync(out1, 0, (size_t)NNODES * DDIM * 4, stream);

  // ---- pass 0: fused score (plain f16, continuous outputs) ----
  fused_score_kernel<0><<<E0N / 64, 512, 0, stream>>>(
      edges0, agg1, rel0, WrtH, WrtL, WctH, WctL, WltH, WltL,
      qtr, qtl, bc, logits0, mkey);

  smax_exp_kernel<<<E0N / 256, 256, 0, stream>>>(edges0, logits0, mkey, ssum, sm0,
                                                 cnt0, E0N);
  smax_norm_kernel<<<E0N / 256, 256, 0, stream>>>(edges0, ssum, sm0, nullptr, nullptr, E0N);
  scatter_kernel<<<E0N / 4, 256, 0, stream>>>(edges0 + 6, 8, edges0 + 7, 8, sm0,
                                              agg1, out1);
  final_mfma_kernel<<<(NNODES + 127) / 128, 512, 0, stream>>>(agg1, out1, cnt0,
                                                              WlnT, blin, out1);
}

// Round 10
// 1050.664 us; speedup vs baseline: 2.3402x; 1.0487x over previous
//
#include <hip/hip_runtime.h>
#include <math.h>

// ---------------------------------------------------------------------------
// AttentionFlow v10.
//  v9 counters: fused_score Mfma 27 / VALU 26 / conflicts 2.7e7 / 1 blk/CU.
//  v10: (1) hi/lo stored as SEPARATE f16 LDS planes -> zero unpack VALU;
//       (2) stage writes iterate PHYSICAL granules (inverse-swizzled global
//           source) -> conflict-free LDS writes; gemm reads granule
//           (ks*4+grp)^(row&7) -> conflict-free reads;
//       (3) T14: A_i gather issued into 64 regs before GEMM1, written to LDS
//           after GEMM2 (latency hidden under ~2/3 of MFMA work).
//  Numerics identical to v9 (same hi/lo split values, same MFMA sequence).
// ---------------------------------------------------------------------------

#define NNODES 100000
#define DDIM   256
#define NH     512
#define NGROUP 64
#define EPG    1024
#define E1N    65536
#define E0N    65536
#define KTOP   256

typedef __attribute__((ext_vector_type(8))) _Float16 h8v;
typedef __attribute__((ext_vector_type(4))) float f32x4;

__device__ __forceinline__ float lrelu(float x) { return x > 0.0f ? x : 0.01f * x; }

__device__ __forceinline__ unsigned fenc(float f) {
  unsigned u = __float_as_uint(f);
  return (u & 0x80000000u) ? ~u : (u | 0x80000000u);
}
__device__ __forceinline__ float fdec(unsigned k) {
  unsigned u = (k & 0x80000000u) ? (k & 0x7FFFFFFFu) : ~k;
  return __uint_as_float(u);
}

__device__ __forceinline__ void splitf(float v, unsigned short& h, unsigned short& l) {
  _Float16 hh = (_Float16)v;
  _Float16 ll = (_Float16)(v - (float)hh);
  h = __builtin_bit_cast(unsigned short, hh);
  l = __builtin_bit_cast(unsigned short, ll);
}

__device__ __forceinline__ f32x4 mfma16(h8v a, h8v b, f32x4 c) {
  return __builtin_amdgcn_mfma_f32_16x16x32_f16(a, b, c, 0, 0, 0);
}

// split 8 f32 (two float4 bit-patterns) -> hi uint4 + lo uint4 (8 f16 each)
__device__ __forceinline__ void pack8(uint4 a, uint4 b, uint4& ph, uint4& pl) {
  float v[8] = {__uint_as_float(a.x), __uint_as_float(a.y),
                __uint_as_float(a.z), __uint_as_float(a.w),
                __uint_as_float(b.x), __uint_as_float(b.y),
                __uint_as_float(b.z), __uint_as_float(b.w)};
  unsigned short h[8], l[8];
#pragma unroll
  for (int d = 0; d < 8; ++d) splitf(v[d], h[d], l[d]);
  ph = make_uint4((unsigned)h[0] | ((unsigned)h[1] << 16),
                  (unsigned)h[2] | ((unsigned)h[3] << 16),
                  (unsigned)h[4] | ((unsigned)h[5] << 16),
                  (unsigned)h[6] | ((unsigned)h[7] << 16));
  pl = make_uint4((unsigned)l[0] | ((unsigned)l[1] << 16),
                  (unsigned)l[2] | ((unsigned)l[3] << 16),
                  (unsigned)l[4] | ((unsigned)l[5] << 16),
                  (unsigned)l[6] | ((unsigned)l[7] << 16));
}

// ---------------------------------------------------------------------------
// qterm[g][o] = b[o] + qs[g] @ W[512:768] + qr[g] @ W[768:1024]
// ---------------------------------------------------------------------------
__global__ __launch_bounds__(512)
void qterm_kernel(const float* __restrict__ qse, const float* __restrict__ qre,
                  const float* __restrict__ Wl, const float* __restrict__ bl,
                  const float* __restrict__ Wr, const float* __restrict__ br,
                  float* __restrict__ qtl, float* __restrict__ qtr)
{
  const int g = blockIdx.x;
  const int o = threadIdx.x;
  __shared__ float sq[DDIM];
  __shared__ float sr[DDIM];
  if (o < DDIM) sq[o] = qse[(size_t)g * DDIM + o];
  else          sr[o - DDIM] = qre[(size_t)g * DDIM + (o - DDIM)];
  __syncthreads();
  float al = bl[o], ar = br[o];
  for (int k = 0; k < DDIM; ++k) {
    float a = sq[k], b = sr[k];
    al += a * Wl[(size_t)(512 + k) * NH + o] + b * Wl[(size_t)(768 + k) * NH + o];
    ar += a * Wr[(size_t)(512 + k) * NH + o] + b * Wr[(size_t)(768 + k) * NH + o];
  }
  qtl[(size_t)g * NH + o] = al;
  qtr[(size_t)g * NH + o] = ar;
}

// ---------------------------------------------------------------------------
// weight prep: Wt{H,L}[o][k] = splitf16(W[k][o]) for Wl[0:512], Wr[0:512], Wc
// ---------------------------------------------------------------------------
__global__ __launch_bounds__(256)
void wprep_kernel(const float* __restrict__ Wl, const float* __restrict__ Wr,
                  const float* __restrict__ Wc,
                  unsigned short* __restrict__ WltH, unsigned short* __restrict__ WltL,
                  unsigned short* __restrict__ WrtH, unsigned short* __restrict__ WrtL,
                  unsigned short* __restrict__ WctH, unsigned short* __restrict__ WctL)
{
  __shared__ float shv[32][33];
  const int mtx = blockIdx.y;
  const int ti = blockIdx.x >> 4;     // k tile
  const int tj = blockIdx.x & 15;     // o tile
  const float* W = mtx == 0 ? Wl : (mtx == 1 ? Wr : Wc);
  unsigned short* OH = mtx == 0 ? WltH : (mtx == 1 ? WrtH : WctH);
  unsigned short* OL = mtx == 0 ? WltL : (mtx == 1 ? WrtL : WctL);
  const int t = threadIdx.x;
  const int r = t >> 3, c4 = (t & 7) * 4;
  *(float4*)&shv[r][c4] = *(const float4*)(W + (size_t)(ti * 32 + r) * 512 + tj * 32 + c4);
  __syncthreads();
  unsigned short h[4], l[4];
#pragma unroll
  for (int q = 0; q < 4; ++q) splitf(shv[c4 + q][r], h[q], l[q]);
  const size_t off = (size_t)(tj * 32 + r) * 512 + ti * 32 + c4;
  *(uint2*)(OH + off) = make_uint2((unsigned)h[0] | ((unsigned)h[1] << 16),
                                   (unsigned)h[2] | ((unsigned)h[3] << 16));
  *(uint2*)(OL + off) = make_uint2((unsigned)l[0] | ((unsigned)l[1] << 16),
                                   (unsigned)l[2] | ((unsigned)l[3] << 16));
}

// WlinT[o][k] = f16(Wlin[k][o]), 256x256, hi only
__global__ __launch_bounds__(256)
void wlinprep_kernel(const float* __restrict__ Wlin, unsigned short* __restrict__ WlinT)
{
  __shared__ float shv[32][33];
  const int ti = blockIdx.x >> 3;    // k tile
  const int tj = blockIdx.x & 7;     // o tile
  const int t = threadIdx.x;
  const int r = t >> 3, c4 = (t & 7) * 4;
  *(float4*)&shv[r][c4] = *(const float4*)(Wlin + (size_t)(ti * 32 + r) * 256 + tj * 32 + c4);
  __syncthreads();
  unsigned short o[4];
#pragma unroll
  for (int q = 0; q < 4; ++q)
    o[q] = __builtin_bit_cast(unsigned short, (_Float16)shv[c4 + q][r]);
  *(uint2*)(WlinT + (size_t)(tj * 32 + r) * 256 + ti * 32 + c4) =
      make_uint2((unsigned)o[0] | ((unsigned)o[1] << 16),
                 (unsigned)o[2] | ((unsigned)o[3] << 16));
}

// ---------------------------------------------------------------------------
// Fused score kernel. Block = 64 edges x 512 cols, 512 thr / 8 waves.
// LDS: hi plane (64 KB) [+ lo plane 64 KB if SPLIT] of f16, granule-swizzled:
//   element (row,k) lives at ushort off = row*512 + ((k>>3)^(row&7))*8 + (k&7).
// Stage threads iterate PHYSICAL granules (q*8+gs) and read the global source
// at the inverse-swizzled logical granule -> conflict-free LDS writes; gemm
// reads granule (ks*4+grp)^(row&7) -> conflict-free b128 reads.
// T14: A_i gathered into 64 regs before GEMM1, written to LDS after GEMM2.
// ---------------------------------------------------------------------------
template<int SPLIT>
__global__ __launch_bounds__(512, 2)
void fused_score_kernel(const int* __restrict__ edges,
                        const float* __restrict__ emb,
                        const float* __restrict__ rel,
                        const unsigned short* __restrict__ BrH,
                        const unsigned short* __restrict__ BrL,
                        const unsigned short* __restrict__ BcH,
                        const unsigned short* __restrict__ BcL,
                        const unsigned short* __restrict__ BlH,
                        const unsigned short* __restrict__ BlL,
                        const float* __restrict__ qtr,
                        const float* __restrict__ qtl,
                        const float* __restrict__ bcv,
                        float* __restrict__ logits,
                        unsigned* __restrict__ mkey)
{
  constexpr int NP = SPLIT ? 2 : 1;
  __shared__ uint4 planesv[NP * 4096];   // [plane][row 64][granule 64] (16B granules)
  __shared__ float red[8][64];
  __shared__ int sidxJ[64], sidxI[64], sgrp[64];

  const int tid  = threadIdx.x;
  const int lane = tid & 63;
  const int w    = tid >> 6;
  const int arow = lane & 15;
  const int grp  = lane >> 4;
  const int col0 = w * 64;
  const int rb   = blockIdx.x * 64;

  // staging mapping: thread = (row, gs); physical granule = q*8+gs
  const int srow = tid >> 3;
  const int gs   = tid & 7;
  const int ssw  = srow & 7;

  if (tid < 64) {
    const int* er = edges + (size_t)(rb + tid) * 8;
    sgrp[tid]  = er[0];
    sidxI[tid] = er[6];
    sidxJ[tid] = er[7];
  }
  __syncthreads();

  const float* baseR = rel + (size_t)(rb + srow) * DDIM - 256;

  // ---- T14: issue A_i gather into registers (consumed after GEMM2) ----
  uint4 ai[16];
  {
    const float* bI = emb + (size_t)sidxI[srow] * DDIM;
#pragma unroll
    for (int q = 0; q < 8; ++q) {
      const int kf = q * 64 + ((gs ^ ssw) << 3);   // logical float offset
      const float* s = (q < 4) ? (bI + kf) : (baseR + kf);
      ai[2 * q]     = ((const uint4*)s)[0];
      ai[2 * q + 1] = ((const uint4*)s)[1];
    }
  }

  // ---- stage A_j directly ----
  {
    const float* bJ = emb + (size_t)sidxJ[srow] * DDIM;
#pragma unroll
    for (int q = 0; q < 8; ++q) {
      const int kf = q * 64 + ((gs ^ ssw) << 3);
      const float* s = (q < 4) ? (bJ + kf) : (baseR + kf);
      uint4 f0 = ((const uint4*)s)[0];
      uint4 f1 = ((const uint4*)s)[1];
      uint4 ph, pl;
      pack8(f0, f1, ph, pl);
      planesv[srow * 64 + q * 8 + gs] = ph;
      if (SPLIT) planesv[4096 + srow * 64 + q * 8 + gs] = pl;
    }
  }
  __syncthreads();

  const unsigned short* hiP = (const unsigned short*)planesv;
  const unsigned short* loP = hiP + 4096 * 8;

  auto gemm = [&](const unsigned short* BH, const unsigned short* BL,
                  f32x4 (&acc)[4][4]) {
    for (int ks = 0; ks < 16; ++ks) {
      const int k0 = ks * 32 + grp * 8;
      h8v bh[4], bl[4];
#pragma unroll
      for (int nt = 0; nt < 4; ++nt) {
        const size_t boff = (size_t)(col0 + nt * 16 + arow) * 512 + k0;
        bh[nt] = *(const h8v*)(BH + boff);
        if (SPLIT) bl[nt] = *(const h8v*)(BL + boff);
      }
#pragma unroll
      for (int mt = 0; mt < 4; ++mt) {
        const int row = mt * 16 + arow;
        const int gh = (ks * 4 + grp) ^ (row & 7);
        h8v h = *(const h8v*)(hiP + row * 512 + gh * 8);
        h8v l;
        if (SPLIT) l = *(const h8v*)(loP + row * 512 + gh * 8);
#pragma unroll
        for (int nt = 0; nt < 4; ++nt) {
          acc[mt][nt] = mfma16(h, bh[nt], acc[mt][nt]);
          if (SPLIT) {
            acc[mt][nt] = mfma16(h, bl[nt], acc[mt][nt]);
            acc[mt][nt] = mfma16(l, bh[nt], acc[mt][nt]);
          }
        }
      }
    }
  };

  // ---- GEMM1: A_j @ WrT ----
  f32x4 a1[4][4];
#pragma unroll
  for (int a = 0; a < 4; ++a)
#pragma unroll
    for (int b = 0; b < 4; ++b) a1[a][b] = (f32x4)0.0f;
  gemm(BrH, BrL, a1);
  __syncthreads();                     // all waves done reading A_j

  // Lr = leaky(a1 + qtr) -> planes (same swizzled layout)
  {
    unsigned short* hiW = (unsigned short*)planesv;
    unsigned short* loW = hiW + 4096 * 8;
#pragma unroll
    for (int mt = 0; mt < 4; ++mt)
#pragma unroll
      for (int nt = 0; nt < 4; ++nt) {
        const int c = col0 + nt * 16 + arow;
#pragma unroll
        for (int reg = 0; reg < 4; ++reg) {
          const int row = mt * 16 + grp * 4 + reg;
          float v = lrelu(a1[mt][nt][reg] + qtr[(size_t)sgrp[row] * NH + c]);
          unsigned short h, l;
          splitf(v, h, l);
          const int off = row * 512 + (((c >> 3) ^ (row & 7)) << 3) + (c & 7);
          hiW[off] = h;
          if (SPLIT) loW[off] = l;
        }
      }
  }
  __syncthreads();

  // ---- GEMM2: Rout = Lr @ WcT + bc (registers) ----
  f32x4 ro[4][4];
#pragma unroll
  for (int a = 0; a < 4; ++a)
#pragma unroll
    for (int b = 0; b < 4; ++b) ro[a][b] = (f32x4)0.0f;
  gemm(BcH, BcL, ro);
#pragma unroll
  for (int nt = 0; nt < 4; ++nt) {
    const float bcval = bcv[col0 + nt * 16 + arow];
#pragma unroll
    for (int mt = 0; mt < 4; ++mt)
#pragma unroll
      for (int reg = 0; reg < 4; ++reg) ro[mt][nt][reg] += bcval;
  }
  __syncthreads();                     // all waves done reading Lr

  // ---- write A_i (from regs) into planes ----
#pragma unroll
  for (int q = 0; q < 8; ++q) {
    uint4 ph, pl;
    pack8(ai[2 * q], ai[2 * q + 1], ph, pl);
    planesv[srow * 64 + q * 8 + gs] = ph;
    if (SPLIT) planesv[4096 + srow * 64 + q * 8 + gs] = pl;
  }
  __syncthreads();

  // ---- GEMM3 + fused dot vs Rout ----
  f32x4 a3[4][4];
#pragma unroll
  for (int a = 0; a < 4; ++a)
#pragma unroll
    for (int b = 0; b < 4; ++b) a3[a][b] = (f32x4)0.0f;
  gemm(BlH, BlL, a3);
#pragma unroll
  for (int mt = 0; mt < 4; ++mt) {
#pragma unroll
    for (int reg = 0; reg < 4; ++reg) {
      const int row = mt * 16 + grp * 4 + reg;
      const int g = sgrp[row];
      float s = 0.0f;
#pragma unroll
      for (int nt = 0; nt < 4; ++nt) {
        const int c = col0 + nt * 16 + arow;
        float v = lrelu(a3[mt][nt][reg] + qtl[(size_t)g * NH + c]);
        s += v * ro[mt][nt][reg];
      }
      s += __shfl_xor(s, 1); s += __shfl_xor(s, 2);
      s += __shfl_xor(s, 4); s += __shfl_xor(s, 8);
      if ((lane & 15) == 0) red[w][row] = s;
    }
  }
  __syncthreads();
  if (tid < 64) {
    float s = 0.0f;
#pragma unroll
    for (int p = 0; p < 8; ++p) s += red[p][tid];   // fixed order
    logits[rb + tid] = s;
    atomicMax(mkey + sidxI[tid], fenc(s));          // segment = er[6]
  }
}

// ---------------------------------------------------------------------------
// segment softmax helpers
// ---------------------------------------------------------------------------
__global__ void smax_exp_kernel(const int* __restrict__ edges, const float* __restrict__ logits,
                                const unsigned* __restrict__ mkey, float* __restrict__ ssum,
                                float* __restrict__ sm, int* __restrict__ cnt, int E)
{
  int e = blockIdx.x * blockDim.x + threadIdx.x;
  if (e < E) {
    int s = edges[(size_t)e * 8 + 6];
    float ev = expf(logits[e] - fdec(mkey[s]));
    sm[e] = ev;
    atomicAdd(ssum + s, ev);
    if (cnt) atomicAdd(cnt + edges[(size_t)e * 8 + 7], 1);
  }
}

__global__ void smax_norm_kernel(const int* __restrict__ edges, const float* __restrict__ ssum,
                                 float* __restrict__ sm, const float* __restrict__ nscore,
                                 float* __restrict__ ta, int E)
{
  int e = blockIdx.x * blockDim.x + threadIdx.x;
  if (e < E) {
    int s = edges[(size_t)e * 8 + 6];
    float v = sm[e] / ssum[s];
    sm[e] = v;
    if (ta) ta[e] = v * nscore[s];
  }
}

// ---------------------------------------------------------------------------
// per-group top-256 of 1024 (desc value, ties -> low idx), bitonic sort
// ---------------------------------------------------------------------------
__global__ __launch_bounds__(256)
void topk_kernel(const float* __restrict__ ta, const float* __restrict__ sm1,
                 const int* __restrict__ edges1,
                 float* __restrict__ out0, float* __restrict__ out2,
                 float* __restrict__ out3, float* __restrict__ smp,
                 int* __restrict__ prn_i, int* __restrict__ prn_j,
                 int* __restrict__ cnt1)
{
  __shared__ float v[EPG];
  __shared__ int   ix[EPG];
  const int g = blockIdx.x, tid = threadIdx.x;
  for (int t = tid; t < EPG; t += 256) { v[t] = ta[(size_t)g * EPG + t]; ix[t] = t; }
  __syncthreads();
  for (int k = 2; k <= EPG; k <<= 1) {
    for (int j = k >> 1; j > 0; j >>= 1) {
      for (int t = tid; t < EPG; t += 256) {
        int l = t ^ j;
        if (l > t) {
          float va = v[t], vb = v[l];
          int ia = ix[t], ib = ix[l];
          bool aFirst = (va > vb) || (va == vb && ia < ib);
          bool up = ((t & k) == 0);
          bool sw = up ? !aFirst : aFirst;
          if (sw) { v[t] = vb; ix[t] = ib; v[l] = va; ix[l] = ia; }
        }
      }
      __syncthreads();
    }
  }
  const int r = tid;
  const int oi = ix[r];
  const float val = v[r];
  const int orig = g * EPG + oi;
  out3[(size_t)g * KTOP + r] = (float)orig;
  const int* er = edges1 + (size_t)orig * 8;
#pragma unroll
  for (int c = 0; c < 8; ++c)
    out2[((size_t)(g * KTOP + r)) * 8 + c] = (float)er[c];
  const int ii = er[6], jj = er[7];
  const float smv = sm1[orig];
  smp[(size_t)g * KTOP + r] = smv;
  prn_i[(size_t)g * KTOP + r] = ii;
  prn_j[(size_t)g * KTOP + r] = jj;
  atomicAdd(out0 + jj, smv * val);
  atomicAdd(cnt1 + jj, 1);
}

// 4 edges per block; thread o = dim o
__global__ void scatter_kernel(const int* __restrict__ idx_i, int si,
                               const int* __restrict__ idx_j, int sj,
                               const float* __restrict__ w,
                               const float* __restrict__ semb,
                               float* __restrict__ agg)
{
  const int e0 = blockIdx.x * 4;
  const int o = threadIdx.x;
#pragma unroll
  for (int q = 0; q < 4; ++q) {
    const int e = e0 + q;
    const int i = idx_i[(size_t)e * si];
    const int j = idx_j[(size_t)e * sj];
    atomicAdd(agg + (size_t)j * DDIM + o, w[e] * semb[(size_t)i * DDIM + o]);
  }
}

__global__ void combine_kernel(const float* __restrict__ mememb, const int* __restrict__ cnt,
                               float* __restrict__ agg)
{
  size_t id = (size_t)blockIdx.x * 256 + threadIdx.x;
  if (cnt[id >> 8] == 0) agg[id] = mememb[id];
}

// ---------------------------------------------------------------------------
// final (MFMA f16): out[r] = leaky( (cnt0[r]>0 ? agg0[r] : emb1[r]) @ Wlin + blin )
// ---------------------------------------------------------------------------
__global__ __launch_bounds__(512)
void final_mfma_kernel(const float* __restrict__ emb1, const float* __restrict__ agg0,
                       const int* __restrict__ cnt0,
                       const unsigned short* __restrict__ WlinT,
                       const float* __restrict__ blin, float* __restrict__ out)
{
  __shared__ int scnt[128];
  const int tid  = threadIdx.x;
  const int lane = tid & 63;
  const int wid  = tid >> 6;
  const int wm = wid >> 2, wn = wid & 3;
  const int rb = blockIdx.x * 128;
  const int arow = lane & 15;
  const int kgrp = (lane >> 4) * 8;
  const int row0 = wm * 64;
  const int col0 = wn * 64;

  if (tid < 128) {
    int r = rb + tid;
    scnt[tid] = (r < NNODES) ? cnt0[(r < NNODES) ? r : 0] : 0;
  }
  __syncthreads();

  f32x4 acc[4][4];
#pragma unroll
  for (int a = 0; a < 4; ++a)
#pragma unroll
    for (int b = 0; b < 4; ++b) acc[a][b] = (f32x4)0.0f;

  for (int ks = 0; ks < 8; ++ks) {
    const int k0 = ks * 32 + kgrp;
    h8v ah[4], bh[4];
#pragma unroll
    for (int nt = 0; nt < 4; ++nt)
      bh[nt] = *(const h8v*)(WlinT + (size_t)(col0 + nt * 16 + arow) * 256 + k0);
#pragma unroll
    for (int mt = 0; mt < 4; ++mt) {
      const int rl = row0 + mt * 16 + arow;
      int r = rb + rl;
      int rc = (r < NNODES) ? r : (NNODES - 1);
      const float* base = (scnt[rl] > 0) ? agg0 : emb1;
      const float* src = base + (size_t)rc * DDIM + k0;
      float4 f0 = *(const float4*)src;
      float4 f1 = *(const float4*)(src + 4);
      float v[8] = {f0.x, f0.y, f0.z, f0.w, f1.x, f1.y, f1.z, f1.w};
      h8v h;
#pragma unroll
      for (int d = 0; d < 8; ++d) h[d] = (_Float16)v[d];
      ah[mt] = h;
    }
#pragma unroll
    for (int mt = 0; mt < 4; ++mt)
#pragma unroll
      for (int nt = 0; nt < 4; ++nt)
        acc[mt][nt] = mfma16(ah[mt], bh[nt], acc[mt][nt]);
  }

  float bl4[4];
#pragma unroll
  for (int nt = 0; nt < 4; ++nt) bl4[nt] = blin[col0 + nt * 16 + arow];

#pragma unroll
  for (int mt = 0; mt < 4; ++mt)
#pragma unroll
    for (int reg = 0; reg < 4; ++reg) {
      const int r = rb + row0 + mt * 16 + (lane >> 4) * 4 + reg;
      if (r < NNODES) {
#pragma unroll
        for (int nt = 0; nt < 4; ++nt) {
          const int c = col0 + nt * 16 + arow;
          out[(size_t)r * DDIM + c] = lrelu(acc[mt][nt][reg] + bl4[nt]);
        }
      }
    }
}

// ---------------------------------------------------------------------------
extern "C" void kernel_launch(void* const* d_in, const int* in_sizes, int n_in,
                              void* d_out, int out_size, void* d_ws, size_t ws_size,
                              hipStream_t stream)
{
  (void)in_sizes; (void)n_in; (void)out_size; (void)ws_size;

  const float* node_score = (const float*)d_in[1];
  const int*   edges0 = (const int*)d_in[2];
  const int*   edges1 = (const int*)d_in[3];
  const float* rel0   = (const float*)d_in[4];
  const float* rel1   = (const float*)d_in[5];
  const float* mememb = (const float*)d_in[6];
  const float* qse    = (const float*)d_in[7];
  const float* qre    = (const float*)d_in[8];
  const float* Wl     = (const float*)d_in[9];
  const float* bl     = (const float*)d_in[10];
  const float* Wr     = (const float*)d_in[11];
  const float* br     = (const float*)d_in[12];
  const float* Wc     = (const float*)d_in[13];
  const float* bc     = (const float*)d_in[14];
  const float* Wlin   = (const float*)d_in[15];
  const float* blin   = (const float*)d_in[16];

  float* out0 = (float*)d_out;
  float* out1 = out0 + NNODES;
  float* out2 = out1 + (size_t)NNODES * DDIM;
  float* out3 = out2 + (size_t)NGROUP * KTOP * 8;

  char* wptr = (char*)d_ws;
  auto alloc = [&](size_t bytes) -> char* {
    char* p = wptr;
    wptr += (bytes + 255) & ~(size_t)255;
    return p;
  };
  float*    qtl     = (float*)alloc((size_t)NGROUP * NH * 4);
  float*    qtr     = (float*)alloc((size_t)NGROUP * NH * 4);
  float*    logits1 = (float*)alloc((size_t)E1N * 4);
  float*    sm1     = (float*)alloc((size_t)E1N * 4);
  float*    ta      = (float*)alloc((size_t)E1N * 4);
  float*    logits0 = (float*)alloc((size_t)E0N * 4);
  float*    sm0     = (float*)alloc((size_t)E0N * 4);
  unsigned* mkey    = (unsigned*)alloc((size_t)NNODES * 4);
  float*    ssum    = (float*)alloc((size_t)NNODES * 4);
  int*      cnt1    = (int*)alloc((size_t)NNODES * 4);
  int*      cnt0    = (int*)alloc((size_t)NNODES * 4);
  float*    smp     = (float*)alloc((size_t)NGROUP * KTOP * 4);
  int*      prn_i   = (int*)alloc((size_t)NGROUP * KTOP * 4);
  int*      prn_j   = (int*)alloc((size_t)NGROUP * KTOP * 4);
  float*    agg1    = (float*)alloc((size_t)NNODES * DDIM * 4);   // emb1

  unsigned short* WltH = (unsigned short*)alloc((size_t)512 * 512 * 2);
  unsigned short* WltL = (unsigned short*)alloc((size_t)512 * 512 * 2);
  unsigned short* WrtH = (unsigned short*)alloc((size_t)512 * 512 * 2);
  unsigned short* WrtL = (unsigned short*)alloc((size_t)512 * 512 * 2);
  unsigned short* WctH = (unsigned short*)alloc((size_t)512 * 512 * 2);
  unsigned short* WctL = (unsigned short*)alloc((size_t)512 * 512 * 2);
  unsigned short* WlnT = (unsigned short*)alloc((size_t)256 * 256 * 2);

  // ---- pass 1 prep ----
  (void)hipMemsetAsync(agg1, 0, (size_t)NNODES * DDIM * 4, stream);
  (void)hipMemsetAsync(cnt1, 0, (size_t)NNODES * 4, stream);
  (void)hipMemsetAsync(mkey, 0, (size_t)NNODES * 4, stream);
  (void)hipMemsetAsync(ssum, 0, (size_t)NNODES * 4, stream);
  (void)hipMemsetAsync(out0, 0, (size_t)NNODES * 4, stream);

  qterm_kernel<<<NGROUP, 512, 0, stream>>>(qse, qre, Wl, bl, Wr, br, qtl, qtr);
  {
    dim3 g(256, 3);
    wprep_kernel<<<g, 256, 0, stream>>>(Wl, Wr, Wc, WltH, WltL, WrtH, WrtL, WctH, WctL);
  }
  wlinprep_kernel<<<64, 256, 0, stream>>>(Wlin, WlnT);

  // ---- pass 1: fused score (split-f16, exact-ish logits for top-k) ----
  fused_score_kernel<1><<<E1N / 64, 512, 0, stream>>>(
      edges1, mememb, rel1, WrtH, WrtL, WctH, WctL, WltH, WltL,
      qtr, qtl, bc, logits1, mkey);

  smax_exp_kernel<<<E1N / 256, 256, 0, stream>>>(edges1, logits1, mkey, ssum, sm1,
                                                 nullptr, E1N);
  smax_norm_kernel<<<E1N / 256, 256, 0, stream>>>(edges1, ssum, sm1, node_score, ta, E1N);
  topk_kernel<<<NGROUP, 256, 0, stream>>>(ta, sm1, edges1, out0, out2, out3,
                                          smp, prn_i, prn_j, cnt1);
  scatter_kernel<<<NGROUP * KTOP / 4, 256, 0, stream>>>(prn_i, 1, prn_j, 1, smp,
                                                        mememb, agg1);
  combine_kernel<<<NNODES, 256, 0, stream>>>(mememb, cnt1, agg1);   // agg1 = emb1

  // ---- pass 0 prep ----
  (void)hipMemsetAsync(mkey, 0, (size_t)NNODES * 4, stream);
  (void)hipMemsetAsync(ssum, 0, (size_t)NNODES * 4, stream);
  (void)hipMemsetAsync(cnt0, 0, (size_t)NNODES * 4, stream);
  (void)hipMemsetAsync(out1, 0, (size_t)NNODES * DDIM * 4, stream);

  // ---- pass 0: fused score (plain f16, continuous outputs) ----
  fused_score_kernel<0><<<E0N / 64, 512, 0, stream>>>(
      edges0, agg1, rel0, WrtH, WrtL, WctH, WctL, WltH, WltL,
      qtr, qtl, bc, logits0, mkey);

  smax_exp_kernel<<<E0N / 256, 256, 0, stream>>>(edges0, logits0, mkey, ssum, sm0,
                                                 cnt0, E0N);
  smax_norm_kernel<<<E0N / 256, 256, 0, stream>>>(edges0, ssum, sm0, nullptr, nullptr, E0N);
  scatter_kernel<<<E0N / 4, 256, 0, stream>>>(edges0 + 6, 8, edges0 + 7, 8, sm0,
                                              agg1, out1);
  final_mfma_kernel<<<(NNODES + 127) / 128, 512, 0, stream>>>(agg1, out1, cnt0,
                                                              WlnT, blin, out1);
}